// Round 1
// baseline (282.834 us; speedup 1.0000x reference)
//
#include <hip/hip_runtime.h>

#define NB 4
#define NR 8
#define NS 8
#define NL 256
#define NH 768
#define NA 256
#define NTD 100

// ---- workspace layout (float offsets) ----
#define WX_F 0
#define WX_B (WX_F + NB*NL*NA)      // 262144
#define WR_F (WX_B + NB*NL*NA)      // 524288
#define WR_B (WR_F + NR*NA)         // 526336
#define WG_F (WR_B + NR*NA)         // 528384
#define WG_B (WG_F + NB*NA)         // 529408
#define C_F  (WG_B + NB*NA)         // 530432  (B,R,H)
#define C_B  (C_F + NB*NR*NH)       // 555008
#define QV   (C_B + NB*NR*NH)       // 579584  8 vectors of 768: q_fs,q_fe,q_bs,q_be,u_fs,u_fe,u_bs,u_be
#define SCAL (QV + 8*NH)            // 585728  8 scalars: bs.ws_f, bs.we_f, bx.ws_f, bx.we_f, bs.ws_b, bs.we_b, bx.ws_b, bx.we_b
#define DXL  (SCAL + 8)             // 585736  4 x (B*L)
#define D1   (DXL + 4*NB*NL)        // 589832  4 x (B*R*S)
#define D3   (D1 + 4*NB*NR*NS)      // 590856  4 x (B*R)

// output offsets (floats)
#define O_FT_S 4096
#define O_FT_E 69632
#define O_BH_S 135168
#define O_BH_E 200704

__device__ __forceinline__ float tanh_fast(float x) {
    x = fminf(15.f, fmaxf(-15.f, x));
    float t = __expf(2.f * x);
    return (t - 1.f) / (t + 1.f);
}

__device__ __forceinline__ float wave_reduce(float v) {
    #pragma unroll
    for (int off = 32; off > 0; off >>= 1) v += __shfl_down(v, off);
    return v;
}

// ---------------- K_pre: wr/wg rows, scalar dots, q/u projection vectors ----------------
__global__ void k_pre(const float* __restrict__ sem, const float* __restrict__ transe,
                      const float* __restrict__ X_mean,
                      const float* __restrict__ fra_Wr, const float* __restrict__ fra_br,
                      const float* __restrict__ fra_Wg, const float* __restrict__ fra_bg,
                      const float* __restrict__ bra_Wr, const float* __restrict__ bra_br,
                      const float* __restrict__ bra_Wg, const float* __restrict__ bra_bg,
                      const float* __restrict__ ffe_Ws, const float* __restrict__ ffe_bs,
                      const float* __restrict__ ffe_Wx, const float* __restrict__ ffe_bx,
                      const float* __restrict__ bfe_Ws, const float* __restrict__ bfe_bs,
                      const float* __restrict__ bfe_Wx, const float* __restrict__ bfe_bx,
                      const float* __restrict__ ft_ws, const float* __restrict__ ft_we,
                      const float* __restrict__ bh_ws, const float* __restrict__ bh_we,
                      float* __restrict__ ws) {
    __shared__ float sh[768];
    const int bid = blockIdx.x, tid = threadIdx.x;

    if (bid < 24) {
        // vec @ mat roles: out[a] = sum_k s[k]*W[k*NA+a] + bias[a]
        const float* s; const float* W; const float* bias; float* out; int K;
        if (bid < 8)       { s = sem + bid*NH;            W = fra_Wr; bias = fra_br; out = ws + WR_F + bid*NA;      K = NH;  }
        else if (bid < 16) { s = transe + (bid-8)*NTD;    W = bra_Wr; bias = bra_br; out = ws + WR_B + (bid-8)*NA;  K = NTD; }
        else if (bid < 20) { s = X_mean + (bid-16)*NH;    W = fra_Wg; bias = fra_bg; out = ws + WG_F + (bid-16)*NA; K = NH;  }
        else               { s = X_mean + (bid-20)*NH;    W = bra_Wg; bias = bra_bg; out = ws + WG_B + (bid-20)*NA; K = NH;  }
        for (int j = tid; j < K; j += 256) sh[j] = s[j];
        __syncthreads();
        float acc = bias[tid];
        for (int k = 0; k < K; ++k) acc += sh[k] * W[k*NA + tid];
        out[tid] = acc;
    } else if (bid < 32) {
        // scalar dots of two 768-vectors
        const float* a; const float* b2;
        switch (bid - 24) {
            case 0: a = ffe_bs; b2 = ft_ws; break;
            case 1: a = ffe_bs; b2 = ft_we; break;
            case 2: a = ffe_bx; b2 = ft_ws; break;
            case 3: a = ffe_bx; b2 = ft_we; break;
            case 4: a = bfe_bs; b2 = bh_ws; break;
            case 5: a = bfe_bs; b2 = bh_we; break;
            case 6: a = bfe_bx; b2 = bh_ws; break;
            default: a = bfe_bx; b2 = bh_we; break;
        }
        float p = a[tid]*b2[tid] + a[tid+256]*b2[tid+256] + a[tid+512]*b2[tid+512];
        sh[tid] = p; __syncthreads();
        for (int s2 = 128; s2 > 0; s2 >>= 1) { if (tid < s2) sh[tid] += sh[tid + s2]; __syncthreads(); }
        if (tid == 0) ws[SCAL + (bid - 24)] = sh[0];
    } else {
        // q/u projection vectors: 8 matvecs (768x768 row-dot), 4 rows per block (1 per wave)
        const int idx = bid - 32;            // 0..1535
        const int mi = idx / 192;            // which matvec
        const int row = (idx % 192)*4 + (tid >> 6);
        const int lane = tid & 63;
        const float* M; const float* v; bool self = false;
        switch (mi) {
            case 0: M = ffe_Ws; v = ft_ws; break;
            case 1: M = ffe_Ws; v = ft_we; break;
            case 2: M = bfe_Ws; v = bh_ws; break;
            case 3: M = bfe_Ws; v = bh_we; break;
            case 4: M = ffe_Wx; v = ft_ws; self = true; break;
            case 5: M = ffe_Wx; v = ft_we; self = true; break;
            case 6: M = bfe_Wx; v = bh_ws; self = true; break;
            default: M = bfe_Wx; v = bh_we; self = true; break;
        }
        const float* mr = M + row*NH;
        float acc = 0.f;
        for (int j = lane; j < NH; j += 64) acc += mr[j] * v[j];
        acc = wave_reduce(acc);
        if (lane == 0) ws[QV + mi*NH + row] = acc + (self ? v[row] : 0.f);
    }
}

// ---------------- K_wx: wx_f / wx_b = X @ W + b  (rows=8 per block, col per thread) ----------------
__global__ void k_wx(const float* __restrict__ X,
                     const float* __restrict__ fra_Wx, const float* __restrict__ fra_bx,
                     const float* __restrict__ bra_Wx, const float* __restrict__ bra_bx,
                     float* __restrict__ ws) {
    __shared__ float xs[8*NH];
    const int bid = blockIdx.x, tid = threadIdx.x;
    const int fb = bid >> 7;                 // 0 = fwd, 1 = bwd
    const int m0 = (bid & 127) * 8;          // first global row (b*L+l)
    const float* W   = fb ? bra_Wx : fra_Wx;
    const float* bia = fb ? bra_bx : fra_bx;
    float* out = ws + (fb ? WX_B : WX_F);

    const float4* src = (const float4*)(X + (size_t)m0*NH);
    float4* dst = (float4*)xs;
    for (int i = tid; i < 8*NH/4; i += 256) dst[i] = src[i];
    __syncthreads();

    float acc[8] = {0,0,0,0,0,0,0,0};
    const float* Wp = W + tid;
    #pragma unroll 4
    for (int h = 0; h < NH; ++h) {
        float w = Wp[h*NA];
        #pragma unroll
        for (int r = 0; r < 8; ++r) acc[r] += xs[r*NH + h] * w;
    }
    const float bb = bia[tid];
    #pragma unroll
    for (int r = 0; r < 8; ++r) out[(size_t)(m0 + r)*NA + tid] = acc[r] + bb;
}

// ---------------- K_attn: e -> softmax -> context c, one block per (fb,b,r) ----------------
__global__ void k_attn(const float* __restrict__ X,
                       const float* __restrict__ fra_V, const float* __restrict__ fra_bv,
                       const float* __restrict__ bra_V, const float* __restrict__ bra_bv,
                       float* __restrict__ ws) {
    __shared__ float wa_s[NA], v_s[NA], e_s[NL], red[NL];
    const int bid = blockIdx.x, t = threadIdx.x;
    const int fb = bid >> 5;
    const int b = (bid >> 3) & 3;
    const int r = bid & 7;

    const float* wr = ws + (fb ? WR_B : WR_F) + r*NA;
    const float* wg = ws + (fb ? WG_B : WG_F) + b*NA;
    const float* V  = fb ? bra_V : fra_V;
    const float  bv = fb ? bra_bv[0] : fra_bv[0];
    const float* wxp = ws + (fb ? WX_B : WX_F);

    wa_s[t] = wr[t] + wg[t];
    v_s[t] = V[t];
    __syncthreads();

    // phase 1: e[l] = sum_a tanh(wx + wr + wg) * V[a] + bv   (thread t owns l=t)
    const float4* wxrow = (const float4*)(wxp + (size_t)(b*NL + t)*NA);
    float acc = 0.f;
    for (int a4 = 0; a4 < NA/4; ++a4) {
        float4 w4 = wxrow[a4];
        int a = a4*4;
        acc += tanh_fast(w4.x + wa_s[a+0]) * v_s[a+0];
        acc += tanh_fast(w4.y + wa_s[a+1]) * v_s[a+1];
        acc += tanh_fast(w4.z + wa_s[a+2]) * v_s[a+2];
        acc += tanh_fast(w4.w + wa_s[a+3]) * v_s[a+3];
    }
    e_s[t] = acc + bv;
    __syncthreads();

    // softmax over l
    red[t] = e_s[t]; __syncthreads();
    for (int s2 = 128; s2 > 0; s2 >>= 1) { if (t < s2) red[t] = fmaxf(red[t], red[t + s2]); __syncthreads(); }
    const float mx = red[0]; __syncthreads();
    const float p = __expf(e_s[t] - mx);
    red[t] = p; __syncthreads();
    for (int s2 = 128; s2 > 0; s2 >>= 1) { if (t < s2) red[t] += red[t + s2]; __syncthreads(); }
    e_s[t] = p / red[0];     // reuse e_s as attention weights
    __syncthreads();

    // phase 2: c[h] = sum_l a[l] * X[b,l,h], thread t covers h = t, t+256, t+512
    const float* Xb = X + (size_t)b*NL*NH;
    float c0 = 0.f, c1 = 0.f, c2 = 0.f;
    for (int l = 0; l < NL; ++l) {
        const float al = e_s[l];
        const float* xr = Xb + (size_t)l*NH;
        c0 += al * xr[t];
        c1 += al * xr[t + 256];
        c2 += al * xr[t + 512];
    }
    float* cc = ws + (fb ? C_B : C_F) + (size_t)(b*NR + r)*NH;
    cc[t] = c0; cc[t + 256] = c1; cc[t + 512] = c2;
}

// ---------------- K_dxl: per (b,l): fh/bt heads to out, X·u dots to ws ----------------
__global__ void k_dxl(const float* __restrict__ X,
                      const float* __restrict__ fh_ws, const float* __restrict__ fh_bs,
                      const float* __restrict__ fh_we, const float* __restrict__ fh_be,
                      const float* __restrict__ bt_ws, const float* __restrict__ bt_bs,
                      const float* __restrict__ bt_we, const float* __restrict__ bt_be,
                      float* __restrict__ ws, float* __restrict__ out) {
    __shared__ float xr[NH];
    const int m = blockIdx.x;      // b*L + l
    const int tid = threadIdx.x, w = tid >> 6, lane = tid & 63;

    const float4* src = (const float4*)(X + (size_t)m*NH);
    float4* dst = (float4*)xr;
    for (int i = tid; i < NH/4; i += 256) dst[i] = src[i];
    __syncthreads();

    const float* v0; const float* v1; float add0, add1; float* o0; float* o1;
    if (w == 0)      { v0 = fh_ws; add0 = fh_bs[0]; o0 = out;        v1 = fh_we; add1 = fh_be[0]; o1 = out + 1024; }
    else if (w == 1) { v0 = bt_ws; add0 = bt_bs[0]; o0 = out + 2048; v1 = bt_we; add1 = bt_be[0]; o1 = out + 3072; }
    else if (w == 2) { v0 = ws + QV + 4*NH; add0 = ws[SCAL+2]; o0 = ws + DXL;
                       v1 = ws + QV + 5*NH; add1 = ws[SCAL+3]; o1 = ws + DXL + 1024; }
    else             { v0 = ws + QV + 6*NH; add0 = ws[SCAL+6]; o0 = ws + DXL + 2048;
                       v1 = ws + QV + 7*NH; add1 = ws[SCAL+7]; o1 = ws + DXL + 3072; }

    float a0 = 0.f, a1 = 0.f;
    for (int j = lane; j < NH; j += 64) { const float x = xr[j]; a0 += x*v0[j]; a1 += x*v1[j]; }
    a0 = wave_reduce(a0); a1 = wave_reduce(a1);
    if (lane == 0) { o0[m] = a0 + add0; o1[m] = a1 + add1; }
}

// ---------------- K_sk: span gather + dots with q vectors; also c·w dots (d3) on s==0 blocks ----------------
__global__ void k_sk(const float* __restrict__ X, const int* __restrict__ sk,
                     const float* __restrict__ sk_mask,
                     const float* __restrict__ ft_ws, const float* __restrict__ ft_we,
                     const float* __restrict__ bh_ws, const float* __restrict__ bh_we,
                     float* __restrict__ ws) {
    __shared__ float avg[NH];
    const int brs = blockIdx.x;                 // (b*8+r)*8+s
    const int tid = threadIdx.x, w = tid >> 6, lane = tid & 63;
    const int b = brs >> 6, br = brs >> 3;
    const int i0 = sk[brs*2], i1 = sk[brs*2 + 1];
    const float mk = sk_mask[brs];

    const float* x0 = X + (size_t)(b*NL + i0)*NH;
    const float* x1 = X + (size_t)(b*NL + i1)*NH;
    for (int j = tid; j < NH; j += 256) avg[j] = 0.5f * (x0[j] + x1[j]);
    __syncthreads();

    // d1[q][brs] = mk*mk*(avg·q) + mk*bsdot[q]
    const float* q = ws + QV + w*NH;
    float acc = 0.f;
    for (int j = lane; j < NH; j += 64) acc += avg[j] * q[j];
    acc = wave_reduce(acc);
    if (lane == 0) {
        const float bsdot = ws[SCAL + ((w < 2) ? w : (w + 2))];   // 0,1,4,5
        ws[D1 + w*(NB*NR*NS) + brs] = mk*mk*acc + mk*bsdot;
    }

    // d3 (c·head) once per (b,r)
    if ((brs & 7) == 0) {
        const float* crow = ws + ((w < 2) ? C_F : C_B) + (size_t)br*NH;
        const float* v = (w == 0) ? ft_ws : (w == 1) ? ft_we : (w == 2) ? bh_ws : bh_we;
        float d = 0.f;
        for (int j = lane; j < NH; j += 64) d += crow[j] * v[j];
        d = wave_reduce(d);
        if (lane == 0) ws[D3 + w*(NB*NR) + br] = d;
    }
}

// ---------------- K_final: broadcast-sum writes of the four (B,R,S,L) outputs ----------------
__global__ void k_final(const float* __restrict__ ft_bs, const float* __restrict__ ft_be,
                        const float* __restrict__ bh_bs, const float* __restrict__ bh_be,
                        const float* __restrict__ ws, float* __restrict__ out) {
    const int brs = blockIdx.x, l = threadIdx.x;
    const int b = brs >> 6, br = brs >> 3;
    const int m = b*NL + l;
    const int o = brs*NL + l;
    out[O_FT_S + o] = ws[D1 + 0*256 + brs] + ws[DXL + 0*1024 + m] + ws[D3 + 0*32 + br] + ft_bs[0];
    out[O_FT_E + o] = ws[D1 + 1*256 + brs] + ws[DXL + 1*1024 + m] + ws[D3 + 1*32 + br] + ft_be[0];
    out[O_BH_S + o] = ws[D1 + 2*256 + brs] + ws[DXL + 2*1024 + m] + ws[D3 + 2*32 + br] + bh_bs[0];
    out[O_BH_E + o] = ws[D1 + 3*256 + brs] + ws[DXL + 3*1024 + m] + ws[D3 + 3*32 + br] + bh_be[0];
}

extern "C" void kernel_launch(void* const* d_in, const int* in_sizes, int n_in,
                              void* d_out, int out_size, void* d_ws, size_t ws_size,
                              hipStream_t stream) {
    const float* X        = (const float*)d_in[0];
    const float* X_mean   = (const float*)d_in[1];
    // d_in[2] = mask (unused by reference)
    const int*   sk       = (const int*)d_in[3];
    const float* sk_mask  = (const float*)d_in[4];
    const float* sem      = (const float*)d_in[5];
    const float* transe   = (const float*)d_in[6];
    const float* fh_ws = (const float*)d_in[7],  *fh_bs = (const float*)d_in[8];
    const float* fh_we = (const float*)d_in[9],  *fh_be = (const float*)d_in[10];
    const float* bt_ws = (const float*)d_in[11], *bt_bs = (const float*)d_in[12];
    const float* bt_we = (const float*)d_in[13], *bt_be = (const float*)d_in[14];
    const float* ft_ws = (const float*)d_in[15], *ft_bs = (const float*)d_in[16];
    const float* ft_we = (const float*)d_in[17], *ft_be = (const float*)d_in[18];
    const float* bh_ws = (const float*)d_in[19], *bh_bs = (const float*)d_in[20];
    const float* bh_we = (const float*)d_in[21], *bh_be = (const float*)d_in[22];
    const float* fra_Wx = (const float*)d_in[23], *fra_bx = (const float*)d_in[24];
    const float* fra_Wr = (const float*)d_in[25], *fra_br = (const float*)d_in[26];
    const float* fra_Wg = (const float*)d_in[27], *fra_bg = (const float*)d_in[28];
    const float* fra_V  = (const float*)d_in[29], *fra_bv = (const float*)d_in[30];
    const float* bra_Wx = (const float*)d_in[31], *bra_bx = (const float*)d_in[32];
    const float* bra_Wr = (const float*)d_in[33], *bra_br = (const float*)d_in[34];
    const float* bra_Wg = (const float*)d_in[35], *bra_bg = (const float*)d_in[36];
    const float* bra_V  = (const float*)d_in[37], *bra_bv = (const float*)d_in[38];
    const float* ffe_Ws = (const float*)d_in[39], *ffe_bs = (const float*)d_in[40];
    const float* ffe_Wx = (const float*)d_in[41], *ffe_bx = (const float*)d_in[42];
    const float* bfe_Ws = (const float*)d_in[43], *bfe_bs = (const float*)d_in[44];
    const float* bfe_Wx = (const float*)d_in[45], *bfe_bx = (const float*)d_in[46];

    float* out = (float*)d_out;
    float* ws  = (float*)d_ws;

    k_pre<<<dim3(1568), dim3(256), 0, stream>>>(sem, transe, X_mean,
        fra_Wr, fra_br, fra_Wg, fra_bg, bra_Wr, bra_br, bra_Wg, bra_bg,
        ffe_Ws, ffe_bs, ffe_Wx, ffe_bx, bfe_Ws, bfe_bs, bfe_Wx, bfe_bx,
        ft_ws, ft_we, bh_ws, bh_we, ws);

    k_wx<<<dim3(256), dim3(256), 0, stream>>>(X, fra_Wx, fra_bx, bra_Wx, bra_bx, ws);

    k_attn<<<dim3(64), dim3(256), 0, stream>>>(X, fra_V, fra_bv, bra_V, bra_bv, ws);

    k_dxl<<<dim3(1024), dim3(256), 0, stream>>>(X, fh_ws, fh_bs, fh_we, fh_be,
        bt_ws, bt_bs, bt_we, bt_be, ws, out);

    k_sk<<<dim3(256), dim3(256), 0, stream>>>(X, sk, sk_mask, ft_ws, ft_we, bh_ws, bh_we, ws);

    k_final<<<dim3(256), dim3(256), 0, stream>>>(ft_bs, ft_be, bh_bs, bh_be, ws, out);
}

// Round 2
// 206.827 us; speedup vs baseline: 1.3675x; 1.3675x over previous
//
#include <hip/hip_runtime.h>
#include <hip/hip_bf16.h>

#define NB 4
#define NR 8
#define NS 8
#define NL 256
#define NH 768
#define NA 256
#define NTD 100

// ---- workspace layout (float offsets) ----
#define WX_F 0
#define WX_B (WX_F + NB*NL*NA)      // 262144
#define WR_F (WX_B + NB*NL*NA)      // 524288
#define WR_B (WR_F + NR*NA)         // 526336
#define WG_F (WR_B + NR*NA)         // 528384
#define WG_B (WG_F + NB*NA)         // 529408
#define C_F  (WG_B + NB*NA)         // 530432  (B,R,H)
#define C_B  (C_F + NB*NR*NH)       // 555008
#define QV   (C_B + NB*NR*NH)       // 579584  8 vectors of 768
#define SCAL (QV + 8*NH)            // 585728  8 scalars
#define DXL  (SCAL + 8)             // 585736  4 x (B*L)
#define D1   (DXL + 4*NB*NL)        // 589832  4 x (B*R*S)
#define D3   (D1 + 4*NB*NR*NS)      // 590856  4 x (B*R)
#define ATT  (D3 + 4*NB*NR)         // 590984  a[fb][b][r][l]  2*4*8*256
#define XB   (ATT + 2*NB*NR*NL)     // 607368  bf16 Xb[1024][768] -> 393216 float slots
#define WT   (XB + (NB*NL*NH)/2)    // 1000584 bf16 Wt[2][256][768] -> 196608 float slots

// output offsets (floats)
#define O_FT_S 4096
#define O_FT_E 69632
#define O_BH_S 135168
#define O_BH_E 200704

typedef __attribute__((ext_vector_type(8))) short short8;
typedef __attribute__((ext_vector_type(4))) float f32x4;

struct bh4 { __hip_bfloat16 a, b, c, d; };

__device__ __forceinline__ float tanh_fast(float x) {
    x = fminf(15.f, fmaxf(-15.f, x));
    float t = __expf(2.f * x);
    return (t - 1.f) / (t + 1.f);
}

__device__ __forceinline__ float wave_reduce(float v) {
    #pragma unroll
    for (int off = 32; off > 0; off >>= 1) v += __shfl_down(v, off);
    return v;
}

// ---------------- K_cvt: X f32->bf16 (row-major) + Wx matrices f32->bf16 transposed ----------------
__global__ void __launch_bounds__(256) k_cvt(const float* __restrict__ X,
                      const float* __restrict__ fra_Wx, const float* __restrict__ bra_Wx,
                      float* __restrict__ ws) {
    __hip_bfloat16* xb = (__hip_bfloat16*)(ws + XB);
    __hip_bfloat16* wt = (__hip_bfloat16*)(ws + WT);
    const int bid = blockIdx.x, tid = threadIdx.x;
    if (bid < 768) {
        const int i0 = bid*1024 + tid*4;
        const float4 v = *(const float4*)(X + i0);
        bh4 o = { __float2bfloat16(v.x), __float2bfloat16(v.y),
                  __float2bfloat16(v.z), __float2bfloat16(v.w) };
        *(bh4*)(xb + i0) = o;
    } else {
        __shared__ float sh[32][33];
        const int t2 = bid - 768;               // 0..383
        const int mt = t2 / 192;                // 0 fwd, 1 bwd
        const int tile = t2 % 192;
        const int h0 = (tile >> 3) * 32, c0 = (tile & 7) * 32;
        const float* W = mt ? bra_Wx : fra_Wx;
        const int r = tid >> 5, c = tid & 31;
        #pragma unroll
        for (int i = 0; i < 4; ++i) {
            const int row = r + 8*i;
            sh[row][c] = W[(size_t)(h0 + row)*NA + c0 + c];
        }
        __syncthreads();
        const int cw = tid >> 5, hw = tid & 31;
        #pragma unroll
        for (int i = 0; i < 4; ++i) {
            const int col = cw + 8*i;
            wt[(size_t)(mt*NA + c0 + col)*NH + h0 + hw] = __float2bfloat16(sh[hw][col]);
        }
    }
}

// ---------------- K_pre ----------------
__global__ void __launch_bounds__(512) k_pre(const float* __restrict__ sem, const float* __restrict__ transe,
                      const float* __restrict__ X_mean,
                      const float* __restrict__ fra_Wr, const float* __restrict__ fra_br,
                      const float* __restrict__ fra_Wg, const float* __restrict__ fra_bg,
                      const float* __restrict__ bra_Wr, const float* __restrict__ bra_br,
                      const float* __restrict__ bra_Wg, const float* __restrict__ bra_bg,
                      const float* __restrict__ ffe_Ws, const float* __restrict__ ffe_bs,
                      const float* __restrict__ ffe_Wx, const float* __restrict__ ffe_bx,
                      const float* __restrict__ bfe_Ws, const float* __restrict__ bfe_bs,
                      const float* __restrict__ bfe_Wx, const float* __restrict__ bfe_bx,
                      const float* __restrict__ ft_ws, const float* __restrict__ ft_we,
                      const float* __restrict__ bh_ws, const float* __restrict__ bh_we,
                      float* __restrict__ ws) {
    __shared__ float sh[768];
    __shared__ float red2[512];
    const int bid = blockIdx.x, tid = threadIdx.x;

    if (bid < 24) {
        // vec @ mat, K split across thread halves
        const float* s; const float* W; const float* bias; float* out; int K;
        if (bid < 8)       { s = sem + bid*NH;         W = fra_Wr; bias = fra_br; out = ws + WR_F + bid*NA;      K = NH;  }
        else if (bid < 16) { s = transe + (bid-8)*NTD; W = bra_Wr; bias = bra_br; out = ws + WR_B + (bid-8)*NA;  K = NTD; }
        else if (bid < 20) { s = X_mean + (bid-16)*NH; W = fra_Wg; bias = fra_bg; out = ws + WG_F + (bid-16)*NA; K = NH;  }
        else               { s = X_mean + (bid-20)*NH; W = bra_Wg; bias = bra_bg; out = ws + WG_B + (bid-20)*NA; K = NH;  }
        for (int j = tid; j < K; j += 512) sh[j] = s[j];
        __syncthreads();
        const int half = tid >> 8, col = tid & 255;
        const int khalf = (K/2) & ~15;
        const int k0 = half ? khalf : 0, k1 = half ? K : khalf;
        const float* Wc = W + col;
        float acc = 0.f;
        int k = k0;
        for (; k + 16 <= k1; k += 16) {
            float wb[16];
            #pragma unroll
            for (int i = 0; i < 16; ++i) wb[i] = Wc[(size_t)(k+i)*NA];
            #pragma unroll
            for (int i = 0; i < 16; ++i) acc += sh[k+i] * wb[i];
        }
        for (; k < k1; ++k) acc += sh[k] * Wc[(size_t)k*NA];
        red2[half*256 + col] = acc;
        __syncthreads();
        if (half == 0) out[col] = red2[col] + red2[256 + col] + bias[col];
    } else if (bid < 32) {
        const float* a; const float* b2;
        switch (bid - 24) {
            case 0: a = ffe_bs; b2 = ft_ws; break;
            case 1: a = ffe_bs; b2 = ft_we; break;
            case 2: a = ffe_bx; b2 = ft_ws; break;
            case 3: a = ffe_bx; b2 = ft_we; break;
            case 4: a = bfe_bs; b2 = bh_ws; break;
            case 5: a = bfe_bs; b2 = bh_we; break;
            case 6: a = bfe_bx; b2 = bh_ws; break;
            default: a = bfe_bx; b2 = bh_we; break;
        }
        float p = a[tid]*b2[tid];
        if (tid < 256) p += a[tid+512]*b2[tid+512];
        red2[tid] = p; __syncthreads();
        for (int s2 = 256; s2 > 0; s2 >>= 1) { if (tid < s2) red2[tid] += red2[tid + s2]; __syncthreads(); }
        if (tid == 0) ws[SCAL + (bid - 24)] = red2[0];
    } else {
        // matvec pairs: mi in 0..3, 8 rows/block (one per wave)
        const int idx = bid - 32;               // 0..383
        const int mi = idx / 96;
        const int row = (idx % 96)*8 + (tid >> 6);
        const int lane = tid & 63;
        const float* M; const float* v0; const float* v1; bool self;
        switch (mi) {
            case 0: M = ffe_Ws; v0 = ft_ws; v1 = ft_we; self = false; break;
            case 1: M = bfe_Ws; v0 = bh_ws; v1 = bh_we; self = false; break;
            case 2: M = ffe_Wx; v0 = ft_ws; v1 = ft_we; self = true;  break;
            default: M = bfe_Wx; v0 = bh_ws; v1 = bh_we; self = true; break;
        }
        const float4* mr4 = (const float4*)(M + (size_t)row*NH);
        const float4* va4 = (const float4*)v0;
        const float4* vb4 = (const float4*)v1;
        float a0 = 0.f, a1 = 0.f;
        #pragma unroll
        for (int i = 0; i < 3; ++i) {
            const float4 m4 = mr4[lane + 64*i];
            const float4 x4 = va4[lane + 64*i];
            const float4 y4 = vb4[lane + 64*i];
            a0 += m4.x*x4.x + m4.y*x4.y + m4.z*x4.z + m4.w*x4.w;
            a1 += m4.x*y4.x + m4.y*y4.y + m4.z*y4.z + m4.w*y4.w;
        }
        a0 = wave_reduce(a0); a1 = wave_reduce(a1);
        if (lane == 0) {
            ws[QV + (mi*2 + 0)*NH + row] = a0 + (self ? v0[row] : 0.f);
            ws[QV + (mi*2 + 1)*NH + row] = a1 + (self ? v1[row] : 0.f);
        }
    }
}

// ---------------- K_wx: bf16 MFMA GEMM  wx = X @ W + b ----------------
__global__ void __launch_bounds__(256) k_wx(const float* __restrict__ fra_bx,
                                            const float* __restrict__ bra_bx,
                                            float* __restrict__ ws) {
    const __hip_bfloat16* xb = (const __hip_bfloat16*)(ws + XB);
    const __hip_bfloat16* wt = (const __hip_bfloat16*)(ws + WT);
    const int bid = blockIdx.x, tid = threadIdx.x;
    const int fb = bid >> 8;
    const int rt = (bid & 255) >> 2, cg = bid & 3;
    const int wv = tid >> 6, lane = tid & 63;
    const int m0 = rt * 16, c0 = cg * 64 + wv * 16;
    const int r16 = lane & 15, koff = (lane >> 4) * 8;

    const short8* ap = (const short8*)(xb + (size_t)(m0 + r16)*NH + koff);
    const short8* bp = (const short8*)(wt + (size_t)(fb*NA + c0 + r16)*NH + koff);

    f32x4 acc = {0.f, 0.f, 0.f, 0.f};
    #pragma unroll
    for (int ks = 0; ks < 24; ks += 4) {
        short8 a0 = ap[(ks+0)*4], b0 = bp[(ks+0)*4];
        short8 a1 = ap[(ks+1)*4], b1 = bp[(ks+1)*4];
        short8 a2 = ap[(ks+2)*4], b2 = bp[(ks+2)*4];
        short8 a3 = ap[(ks+3)*4], b3 = bp[(ks+3)*4];
        acc = __builtin_amdgcn_mfma_f32_16x16x32_bf16(a0, b0, acc, 0, 0, 0);
        acc = __builtin_amdgcn_mfma_f32_16x16x32_bf16(a1, b1, acc, 0, 0, 0);
        acc = __builtin_amdgcn_mfma_f32_16x16x32_bf16(a2, b2, acc, 0, 0, 0);
        acc = __builtin_amdgcn_mfma_f32_16x16x32_bf16(a3, b3, acc, 0, 0, 0);
    }
    const float* bia = fb ? bra_bx : fra_bx;
    float* outp = ws + (fb ? WX_B : WX_F);
    const int col = c0 + r16;
    const float bb = bia[col];
    const int rbase = m0 + (lane >> 4) * 4;
    #pragma unroll
    for (int j = 0; j < 4; ++j)
        outp[(size_t)(rbase + j)*NA + col] = acc[j] + bb;
}

// ---------------- K_attn: e -> softmax -> a (stored to ws ATT) ----------------
__global__ void __launch_bounds__(512) k_attn(const float* __restrict__ fra_V, const float* __restrict__ fra_bv,
                       const float* __restrict__ bra_V, const float* __restrict__ bra_bv,
                       float* __restrict__ ws) {
    __shared__ float wa_s[NA], v_s[NA], red[NL], part[NL];
    const int bid = blockIdx.x, tid = threadIdx.x;
    const int fb = bid >> 5, b = (bid >> 3) & 3, r = bid & 7;
    const int l = tid & 255, half = tid >> 8;

    const float* wr = ws + (fb ? WR_B : WR_F) + r*NA;
    const float* wg = ws + (fb ? WG_B : WG_F) + b*NA;
    const float* V  = fb ? bra_V : fra_V;
    const float  bv = fb ? bra_bv[0] : fra_bv[0];
    const float* wxp = ws + (fb ? WX_B : WX_F);

    if (tid < 256) { wa_s[tid] = wr[tid] + wg[tid]; v_s[tid] = V[tid]; }
    __syncthreads();

    // e[l] over half the A range per thread-half
    const float4* wxrow = (const float4*)(wxp + (size_t)(b*NL + l)*NA + half*128);
    float acc = 0.f;
    for (int a0 = 0; a0 < 32; a0 += 8) {
        float4 wb[8];
        #pragma unroll
        for (int i = 0; i < 8; ++i) wb[i] = wxrow[a0 + i];
        #pragma unroll
        for (int i = 0; i < 8; ++i) {
            const int a = half*128 + (a0 + i)*4;
            acc += tanh_fast(wb[i].x + wa_s[a+0]) * v_s[a+0];
            acc += tanh_fast(wb[i].y + wa_s[a+1]) * v_s[a+1];
            acc += tanh_fast(wb[i].z + wa_s[a+2]) * v_s[a+2];
            acc += tanh_fast(wb[i].w + wa_s[a+3]) * v_s[a+3];
        }
    }
    if (half) part[l] = acc;
    __syncthreads();

    float e = 0.f;
    if (!half) e = acc + part[l] + bv;
    if (tid < 256) red[tid] = e;
    __syncthreads();
    for (int s2 = 128; s2 > 0; s2 >>= 1) { if (tid < s2) red[tid] = fmaxf(red[tid], red[tid+s2]); __syncthreads(); }
    const float mx = red[0];
    __syncthreads();
    float p = 0.f;
    if (tid < 256) { p = __expf(e - mx); red[tid] = p; }
    __syncthreads();
    for (int s2 = 128; s2 > 0; s2 >>= 1) { if (tid < s2) red[tid] += red[tid+s2]; __syncthreads(); }
    if (tid < 256)
        ws[ATT + ((size_t)(fb*NB + b)*NR + r)*NL + tid] = p / red[0];
}

// ---------------- K_ctx: c[ctx][h] = sum_l a[l] X[b][l][h] ----------------
__global__ void __launch_bounds__(256) k_ctx(const float* __restrict__ X, float* __restrict__ ws) {
    __shared__ float a_s[NL];
    const int bid = blockIdx.x, tid = threadIdx.x;
    const int hc = bid % 3;
    const int r  = (bid / 3) & 7;
    const int b  = (bid / 24) & 3;
    const int fb = bid / 96;

    a_s[tid] = ws[ATT + ((size_t)(fb*NB + b)*NR + r)*NL + tid];
    __syncthreads();

    const float* Xp = X + (size_t)b*NL*NH + hc*256 + tid;
    float c = 0.f;
    for (int l0 = 0; l0 < NL; l0 += 8) {
        float xb_[8];
        #pragma unroll
        for (int i = 0; i < 8; ++i) xb_[i] = Xp[(size_t)(l0+i)*NH];
        #pragma unroll
        for (int i = 0; i < 8; ++i) c += a_s[l0+i] * xb_[i];
    }
    ws[(fb ? C_B : C_F) + (size_t)(b*NR + r)*NH + hc*256 + tid] = c;
}

// ---------------- K_dxl: per (b,l): fh/bt heads to out, X·u dots to ws ----------------
__global__ void __launch_bounds__(256) k_dxl(const float* __restrict__ X,
                      const float* __restrict__ fh_ws, const float* __restrict__ fh_bs,
                      const float* __restrict__ fh_we, const float* __restrict__ fh_be,
                      const float* __restrict__ bt_ws, const float* __restrict__ bt_bs,
                      const float* __restrict__ bt_we, const float* __restrict__ bt_be,
                      float* __restrict__ ws, float* __restrict__ out) {
    __shared__ float xr[NH];
    const int m = blockIdx.x;      // b*L + l
    const int tid = threadIdx.x, w = tid >> 6, lane = tid & 63;

    if (tid < 192) ((float4*)xr)[tid] = ((const float4*)(X + (size_t)m*NH))[tid];
    __syncthreads();

    const float* v0; const float* v1; float add0, add1; float* o0; float* o1;
    if (w == 0)      { v0 = fh_ws; add0 = fh_bs[0]; o0 = out;        v1 = fh_we; add1 = fh_be[0]; o1 = out + 1024; }
    else if (w == 1) { v0 = bt_ws; add0 = bt_bs[0]; o0 = out + 2048; v1 = bt_we; add1 = bt_be[0]; o1 = out + 3072; }
    else if (w == 2) { v0 = ws + QV + 4*NH; add0 = ws[SCAL+2]; o0 = ws + DXL;
                       v1 = ws + QV + 5*NH; add1 = ws[SCAL+3]; o1 = ws + DXL + 1024; }
    else             { v0 = ws + QV + 6*NH; add0 = ws[SCAL+6]; o0 = ws + DXL + 2048;
                       v1 = ws + QV + 7*NH; add1 = ws[SCAL+7]; o1 = ws + DXL + 3072; }

    const float4* xr4 = (const float4*)xr;
    const float4* v04 = (const float4*)v0;
    const float4* v14 = (const float4*)v1;
    float a0 = 0.f, a1 = 0.f;
    #pragma unroll
    for (int i = 0; i < 3; ++i) {
        const float4 x4 = xr4[lane + 64*i];
        const float4 p4 = v04[lane + 64*i];
        const float4 q4 = v14[lane + 64*i];
        a0 += x4.x*p4.x + x4.y*p4.y + x4.z*p4.z + x4.w*p4.w;
        a1 += x4.x*q4.x + x4.y*q4.y + x4.z*q4.z + x4.w*q4.w;
    }
    a0 = wave_reduce(a0); a1 = wave_reduce(a1);
    if (lane == 0) { o0[m] = a0 + add0; o1[m] = a1 + add1; }
}

// ---------------- K_sk: span gather + dots with q vectors; c·head dots on s==0 ----------------
__global__ void __launch_bounds__(256) k_sk(const float* __restrict__ X, const int* __restrict__ sk,
                     const float* __restrict__ sk_mask,
                     const float* __restrict__ ft_ws, const float* __restrict__ ft_we,
                     const float* __restrict__ bh_ws, const float* __restrict__ bh_we,
                     float* __restrict__ ws) {
    __shared__ float avg[NH];
    const int brs = blockIdx.x;
    const int tid = threadIdx.x, w = tid >> 6, lane = tid & 63;
    const int b = brs >> 6, br = brs >> 3;
    const int i0 = sk[brs*2], i1 = sk[brs*2 + 1];
    const float mk = sk_mask[brs];

    if (tid < 192) {
        const float4 x0 = ((const float4*)(X + (size_t)(b*NL + i0)*NH))[tid];
        const float4 x1 = ((const float4*)(X + (size_t)(b*NL + i1)*NH))[tid];
        float4 o; o.x = 0.5f*(x0.x+x1.x); o.y = 0.5f*(x0.y+x1.y);
        o.z = 0.5f*(x0.z+x1.z); o.w = 0.5f*(x0.w+x1.w);
        ((float4*)avg)[tid] = o;
    }
    __syncthreads();

    const float4* q4 = (const float4*)(ws + QV + w*NH);
    const float4* av4 = (const float4*)avg;
    float acc = 0.f;
    #pragma unroll
    for (int i = 0; i < 3; ++i) {
        const float4 a4 = av4[lane + 64*i];
        const float4 b4 = q4[lane + 64*i];
        acc += a4.x*b4.x + a4.y*b4.y + a4.z*b4.z + a4.w*b4.w;
    }
    acc = wave_reduce(acc);
    if (lane == 0) {
        const float bsdot = ws[SCAL + ((w < 2) ? w : (w + 2))];
        ws[D1 + w*(NB*NR*NS) + brs] = mk*mk*acc + mk*bsdot;
    }

    if ((brs & 7) == 0) {
        const float4* c4 = (const float4*)(ws + ((w < 2) ? C_F : C_B) + (size_t)br*NH);
        const float* v = (w == 0) ? ft_ws : (w == 1) ? ft_we : (w == 2) ? bh_ws : bh_we;
        const float4* vv4 = (const float4*)v;
        float d = 0.f;
        #pragma unroll
        for (int i = 0; i < 3; ++i) {
            const float4 a4 = c4[lane + 64*i];
            const float4 b4 = vv4[lane + 64*i];
            d += a4.x*b4.x + a4.y*b4.y + a4.z*b4.z + a4.w*b4.w;
        }
        d = wave_reduce(d);
        if (lane == 0) ws[D3 + w*(NB*NR) + br] = d;
    }
}

// ---------------- K_final ----------------
__global__ void __launch_bounds__(256) k_final(const float* __restrict__ ft_bs, const float* __restrict__ ft_be,
                        const float* __restrict__ bh_bs, const float* __restrict__ bh_be,
                        const float* __restrict__ ws, float* __restrict__ out) {
    const int brs = blockIdx.x, l = threadIdx.x;
    const int b = brs >> 6, br = brs >> 3;
    const int m = b*NL + l;
    const int o = brs*NL + l;
    out[O_FT_S + o] = ws[D1 + 0*256 + brs] + ws[DXL + 0*1024 + m] + ws[D3 + 0*32 + br] + ft_bs[0];
    out[O_FT_E + o] = ws[D1 + 1*256 + brs] + ws[DXL + 1*1024 + m] + ws[D3 + 1*32 + br] + ft_be[0];
    out[O_BH_S + o] = ws[D1 + 2*256 + brs] + ws[DXL + 2*1024 + m] + ws[D3 + 2*32 + br] + bh_bs[0];
    out[O_BH_E + o] = ws[D1 + 3*256 + brs] + ws[DXL + 3*1024 + m] + ws[D3 + 3*32 + br] + bh_be[0];
}

extern "C" void kernel_launch(void* const* d_in, const int* in_sizes, int n_in,
                              void* d_out, int out_size, void* d_ws, size_t ws_size,
                              hipStream_t stream) {
    const float* X        = (const float*)d_in[0];
    const float* X_mean   = (const float*)d_in[1];
    const int*   sk       = (const int*)d_in[3];
    const float* sk_mask  = (const float*)d_in[4];
    const float* sem      = (const float*)d_in[5];
    const float* transe   = (const float*)d_in[6];
    const float* fh_ws = (const float*)d_in[7],  *fh_bs = (const float*)d_in[8];
    const float* fh_we = (const float*)d_in[9],  *fh_be = (const float*)d_in[10];
    const float* bt_ws = (const float*)d_in[11], *bt_bs = (const float*)d_in[12];
    const float* bt_we = (const float*)d_in[13], *bt_be = (const float*)d_in[14];
    const float* ft_ws = (const float*)d_in[15], *ft_bs = (const float*)d_in[16];
    const float* ft_we = (const float*)d_in[17], *ft_be = (const float*)d_in[18];
    const float* bh_ws = (const float*)d_in[19], *bh_bs = (const float*)d_in[20];
    const float* bh_we = (const float*)d_in[21], *bh_be = (const float*)d_in[22];
    const float* fra_Wx = (const float*)d_in[23], *fra_bx = (const float*)d_in[24];
    const float* fra_Wr = (const float*)d_in[25], *fra_br = (const float*)d_in[26];
    const float* fra_Wg = (const float*)d_in[27], *fra_bg = (const float*)d_in[28];
    const float* fra_V  = (const float*)d_in[29], *fra_bv = (const float*)d_in[30];
    const float* bra_Wx = (const float*)d_in[31], *bra_bx = (const float*)d_in[32];
    const float* bra_Wr = (const float*)d_in[33], *bra_br = (const float*)d_in[34];
    const float* bra_Wg = (const float*)d_in[35], *bra_bg = (const float*)d_in[36];
    const float* bra_V  = (const float*)d_in[37], *bra_bv = (const float*)d_in[38];
    const float* ffe_Ws = (const float*)d_in[39], *ffe_bs = (const float*)d_in[40];
    const float* ffe_Wx = (const float*)d_in[41], *ffe_bx = (const float*)d_in[42];
    const float* bfe_Ws = (const float*)d_in[43], *bfe_bs = (const float*)d_in[44];
    const float* bfe_Wx = (const float*)d_in[45], *bfe_bx = (const float*)d_in[46];

    float* out = (float*)d_out;
    float* ws  = (float*)d_ws;

    k_cvt<<<dim3(1152), dim3(256), 0, stream>>>(X, fra_Wx, bra_Wx, ws);

    k_pre<<<dim3(416), dim3(512), 0, stream>>>(sem, transe, X_mean,
        fra_Wr, fra_br, fra_Wg, fra_bg, bra_Wr, bra_br, bra_Wg, bra_bg,
        ffe_Ws, ffe_bs, ffe_Wx, ffe_bx, bfe_Ws, bfe_bs, bfe_Wx, bfe_bx,
        ft_ws, ft_we, bh_ws, bh_we, ws);

    k_wx<<<dim3(512), dim3(256), 0, stream>>>(fra_bx, bra_bx, ws);

    k_attn<<<dim3(64), dim3(512), 0, stream>>>(fra_V, fra_bv, bra_V, bra_bv, ws);

    k_ctx<<<dim3(192), dim3(256), 0, stream>>>(X, ws);

    k_dxl<<<dim3(1024), dim3(256), 0, stream>>>(X, fh_ws, fh_bs, fh_we, fh_be,
        bt_ws, bt_bs, bt_we, bt_be, ws, out);

    k_sk<<<dim3(256), dim3(256), 0, stream>>>(X, sk, sk_mask, ft_ws, ft_we, bh_ws, bh_we, ws);

    k_final<<<dim3(256), dim3(256), 0, stream>>>(ft_bs, ft_be, bh_bs, bh_be, ws, out);
}